// Round 8
// baseline (227.126 us; speedup 1.0000x reference)
//
#include <hip/hip_runtime.h>

#define CGN    4096
#define NBLK   256
#define NTHR   1024
#define NW     (NTHR / 64)       // 16 waves/block
#define RPB    (CGN / NBLK)      // 16 rows/elements owned per block
#define MAX_IT 20
#define TOLF   1e-8f

typedef float f32x4 __attribute__((ext_vector_type(4)));

// Module-scope scratch (.bss). Deterministic: fully rewritten or monotonic.
__device__ float    g_r[CGN];
__device__ float    g_part_pAp[NBLK];
__device__ float    g_part_rs[NBLK];
__device__ unsigned g_flags[NBLK];  // per-block arrival epochs (monotonic)

// Coherence-point (L3) accesses for cross-block data. RELAXED => no cache
// maintenance instructions; AGENT scope => sc-flagged, bypass stale L1/L2.
#define AL(p)   __hip_atomic_load((p), __ATOMIC_RELAXED, __HIP_MEMORY_SCOPE_AGENT)
#define AS(p,v) __hip_atomic_store((p), (v), __ATOMIC_RELAXED, __HIP_MEMORY_SCOPE_AGENT)

__device__ __forceinline__ float wave_reduce(float v) {
    #pragma unroll
    for (int off = 32; off > 0; off >>= 1)
        v += __shfl_down(v, off, 64);
    return v;  // lane 0 holds the sum
}

// Single-hop flag barrier: arrival = one sc-store per block; thread i<NBLK of
// EVERY block polls g_flags[i] directly (no release hop). Monotonic epochs =>
// wrap-safe, no reset, replay-safe. __syncthreads() before arrival drains
// vmcnt so all data stores reached the coherence point first.
__device__ __forceinline__ void grid_barrier(int tid, int blk, unsigned target) {
    __syncthreads();
    if (tid == 0) AS(&g_flags[blk], target);
    if (tid < NBLK) {
        while ((int)(AL(&g_flags[tid]) - target) < 0)
            __builtin_amdgcn_s_sleep(2);
    }
    __syncthreads();
}

__global__ __launch_bounds__(NTHR, 4) void pcg_kernel(
    const float* __restrict__ A, const float* __restrict__ b,
    float* __restrict__ x)
{
    __shared__ float p_lds[CGN];   // persistent p vector (block-local copy)
    __shared__ float ap_lds[NW];   // Ap for own rows (row = blk*RPB + wv)
    __shared__ float red[NW];

    const int tid  = threadIdx.x;
    const int blk  = blockIdx.x;
    const int lane = tid & 63;
    const int wv   = tid >> 6;

    const unsigned base = AL(&g_flags[blk]);  // flags all equal between calls
    unsigned bc = 0;

    // ---- pin own A row-slice in 64 VGPRs via asm loads (not rematerializable) ----
    f32x4 arow[16];
    {
        const f32x4* bp = (const f32x4*)(A + (size_t)(blk * RPB + wv) * CGN) + lane;
        #pragma unroll
        for (int j = 0; j < 16; ++j) {
            const f32x4* addr = bp + j * 64;
            asm volatile("global_load_dwordx4 %0, %1, off"
                         : "=v"(arow[j]) : "v"(addr));
        }
    }

    // ---- init own RPB elements: r = b, partial b.b (overlaps with A loads) ----
    float r_own = 0.f, x_own = 0.f;      // live in wave 0, lanes < RPB
    if (wv == 0) {
        float sq = 0.f;
        if (lane < RPB) {
            int e = blk * RPB + lane;
            r_own = b[e];
            AS(&g_r[e], r_own);
            sq = r_own * r_own;
        }
        sq = wave_reduce(sq);
        if (lane == 0) AS(&g_part_rs[blk], sq);
    }

    asm volatile("s_waitcnt vmcnt(0)" ::: "memory");
    __builtin_amdgcn_sched_barrier(0);   // keep arow uses below the waitcnt

    grid_barrier(tid, blk, base + (++bc));

    float rs_old = 0.f;
    for (int k = 0; k < MAX_IT; ++k) {
        // ---- all-reduce part_rs -> rs (identical order in every block) ----
        float v = (tid < NBLK) ? AL(&g_part_rs[tid]) : 0.f;
        v = wave_reduce(v);
        if (lane == 0) red[wv] = v;
        __syncthreads();
        float rs = 0.f;
        #pragma unroll
        for (int i = 0; i < NW; ++i) rs += red[i];
        __syncthreads();

        if (!(rs >= TOLF * TOLF)) break;   // uniform across grid

        float bk = (k == 0) ? 0.f : rs / rs_old;
        rs_old = rs;

        // ---- p = r + bk*p (p persistent in LDS; k==0: p = r, LDS garbage guard) ----
        {
            int i0 = tid * 4;
            float r0 = AL(&g_r[i0 + 0]);
            float r1 = AL(&g_r[i0 + 1]);
            float r2 = AL(&g_r[i0 + 2]);
            float r3 = AL(&g_r[i0 + 3]);
            float p0, p1, p2, p3;
            if (k == 0) {
                p0 = r0; p1 = r1; p2 = r2; p3 = r3;
            } else {
                p0 = r0 + bk * p_lds[i0 + 0];
                p1 = r1 + bk * p_lds[i0 + 1];
                p2 = r2 + bk * p_lds[i0 + 2];
                p3 = r3 + bk * p_lds[i0 + 3];
            }
            p_lds[i0 + 0] = p0;
            p_lds[i0 + 1] = p1;
            p_lds[i0 + 2] = p2;
            p_lds[i0 + 3] = p3;
        }
        __syncthreads();

        // ---- matvec from REGISTERS: wave wv computes row blk*RPB + wv ----
        float acc = 0.f;
        #pragma unroll
        for (int j = 0; j < 16; ++j) {
            f32x4 p4 = *(const f32x4*)&p_lds[(j * 64 + lane) * 4];
            acc += arow[j][0] * p4[0] + arow[j][1] * p4[1]
                 + arow[j][2] * p4[2] + arow[j][3] * p4[3];
        }
        acc = wave_reduce(acc);
        if (lane == 0) ap_lds[wv] = acc;
        __syncthreads();

        // ---- own partial of p.Ap (wave 0) ----
        if (wv == 0) {
            float d = 0.f;
            if (lane < RPB) d = p_lds[blk * RPB + lane] * ap_lds[lane];
            d = wave_reduce(d);
            if (lane == 0) AS(&g_part_pAp[blk], d);
        }
        grid_barrier(tid, blk, base + (++bc));   // S1: part_pAp published

        // ---- all-reduce part_pAp -> pAp; ak; local update of own r, x ----
        float u = (tid < NBLK) ? AL(&g_part_pAp[tid]) : 0.f;
        u = wave_reduce(u);
        if (lane == 0) red[wv] = u;
        __syncthreads();
        float pAp = 0.f;
        #pragma unroll
        for (int i = 0; i < NW; ++i) pAp += red[i];
        __syncthreads();

        float ak = rs / pAp;
        if (wv == 0) {
            float sq = 0.f;
            if (lane < RPB) {
                int e = blk * RPB + lane;
                x_own += ak * p_lds[e];
                r_own -= ak * ap_lds[lane];
                AS(&g_r[e], r_own);
                sq = r_own * r_own;
            }
            sq = wave_reduce(sq);
            if (lane == 0) AS(&g_part_rs[blk], sq);
        }
        grid_barrier(tid, blk, base + (++bc));   // S2: r, part_rs published
    }

    // ---- write own x elements once ----
    if (wv == 0 && lane < RPB) x[blk * RPB + lane] = x_own;
}

extern "C" void kernel_launch(void* const* d_in, const int* in_sizes, int n_in,
                              void* d_out, int out_size, void* d_ws, size_t ws_size,
                              hipStream_t stream) {
    const float* A = (const float*)d_in[0];
    const float* b = (const float*)d_in[1];
    float* x = (float*)d_out;
    pcg_kernel<<<dim3(NBLK), dim3(NTHR), 0, stream>>>(A, b, x);
}

// Round 9
// 143.239 us; speedup vs baseline: 1.5856x; 1.5856x over previous
//
#include <hip/hip_runtime.h>

#define CGN    4096
#define NBLK   256
#define NTHR   1024
#define NW     (NTHR / 64)       // 16 waves/block
#define RPB    (CGN / NBLK)      // 16 rows per block (1 per wave)
#define MAX_IT 20
#define TOLF   1e-8f

typedef float f32x4 __attribute__((ext_vector_type(4)));

// Module-scope scratch (.bss). Deterministic: fully rewritten or monotonic.
// g_Ap / g_part are parity double-buffered: with one barrier per iteration a
// block lags at most one publish behind, so the other buffer is never racing.
__device__ float    g_Ap[2][CGN];
__device__ float    g_part[2][NBLK];
__device__ unsigned g_flags[NBLK];  // per-block arrival epochs (monotonic)
__device__ unsigned g_release;      // block-0-owned release epoch (monotonic)

// Coherence-point (L3) accesses for cross-block data. RELAXED => no cache
// maintenance instructions; AGENT scope => sc-flagged, bypass stale L1/L2.
#define AL(p)   __hip_atomic_load((p), __ATOMIC_RELAXED, __HIP_MEMORY_SCOPE_AGENT)
#define AS(p,v) __hip_atomic_store((p), (v), __ATOMIC_RELAXED, __HIP_MEMORY_SCOPE_AGENT)

__device__ __forceinline__ float wave_reduce(float v) {
    #pragma unroll
    for (int off = 32; off > 0; off >>= 1)
        v += __shfl_down(v, off, 64);
    return v;  // lane 0 holds the sum
}

// Block-wide sum, result returned to ALL threads. Entry sync protects the
// previous use of `red`. Identical inputs + identical order in every block
// => bit-identical result grid-wide (uniform control flow on rs, ak, bk).
__device__ __forceinline__ float block_sum(float v, float* red, int lane, int wv) {
    float s = wave_reduce(v);
    __syncthreads();
    if (lane == 0) red[wv] = s;
    __syncthreads();
    float t = 0.f;
    #pragma unroll
    for (int i = 0; i < NW; ++i) t += red[i];
    return t;
}

// Hierarchical flag barrier (round-7 proven): arrival = one sc-store/block;
// block 0 polls all flags then publishes one release word; others poll only
// the release word. __syncthreads() before arrival drains vmcnt, so all data
// stores reached the coherence point first. Monotonic epochs => replay-safe.
__device__ __forceinline__ void grid_barrier(int blk, int tid, unsigned target) {
    __syncthreads();
    if (tid == 0) AS(&g_flags[blk], target);
    if (blk == 0) {
        if (tid < NBLK) {
            while ((int)(AL(&g_flags[tid]) - target) < 0)
                __builtin_amdgcn_s_sleep(2);
        }
        __syncthreads();                 // all 256 flags confirmed
        if (tid == 0) AS(&g_release, target);
    } else {
        if (tid == 0) {
            while ((int)(AL(&g_release) - target) < 0)
                __builtin_amdgcn_s_sleep(2);
        }
    }
    __syncthreads();
}

__global__ __launch_bounds__(NTHR, 4) void pcg_kernel(
    const float* __restrict__ A, const float* __restrict__ b,
    float* __restrict__ x)
{
    __shared__ float p_lds[CGN];   // full p vector (redundant per block)
    __shared__ float ap_lds[NW];   // Ap of own rows (row = blk*RPB + wv)
    __shared__ float red[NW];

    const int tid  = threadIdx.x;
    const int blk  = blockIdx.x;
    const int lane = tid & 63;
    const int wv   = tid >> 6;
    const int e0   = tid * 4;                 // this thread's 4 elements
    const bool owner = (tid >> 2) == blk;     // 4 threads own the block's x-slice

    const unsigned base = AL(&g_flags[blk]);  // flags all equal between calls
    unsigned bc = 0;

    // ---- pin own A row-slice in 64 VGPRs via asm loads (not rematerializable) ----
    f32x4 arow[16];
    {
        const f32x4* bp = (const f32x4*)(A + (size_t)(blk * RPB + wv) * CGN) + lane;
        #pragma unroll
        for (int j = 0; j < 16; ++j) {
            const f32x4* addr = bp + j * 64;
            asm volatile("global_load_dwordx4 %0, %1, off"
                         : "=v"(arow[j]) : "v"(addr));
        }
    }

    // ---- init: full r in regs (= b), full p in LDS (= b), rs = b.b locally ----
    f32x4 r_reg = ((const f32x4*)b)[tid];
    f32x4 x_reg = {0.f, 0.f, 0.f, 0.f};
    *(f32x4*)&p_lds[e0] = r_reg;
    float rs = block_sum(r_reg[0]*r_reg[0] + r_reg[1]*r_reg[1]
                       + r_reg[2]*r_reg[2] + r_reg[3]*r_reg[3], red, lane, wv);

    asm volatile("s_waitcnt vmcnt(0)" ::: "memory");
    __builtin_amdgcn_sched_barrier(0);   // arow valid below this point

    for (int k = 0; k < MAX_IT; ++k) {
        if (!(rs >= TOLF * TOLF)) break;   // uniform across grid
        const int buf = k & 1;

        // ---- matvec from registers: wave wv computes row blk*RPB + wv ----
        float acc = 0.f;
        #pragma unroll
        for (int j = 0; j < 16; ++j) {
            f32x4 p4 = *(const f32x4*)&p_lds[(j * 64 + lane) * 4];
            acc += arow[j][0] * p4[0] + arow[j][1] * p4[1]
                 + arow[j][2] * p4[2] + arow[j][3] * p4[3];
        }
        acc = wave_reduce(acc);
        if (lane == 0) {
            ap_lds[wv] = acc;
            AS(&g_Ap[buf][blk * RPB + wv], acc);   // publish own Ap element
        }
        __syncthreads();

        // ---- own partial of p.Ap ----
        if (wv == 0) {
            float d = (lane < RPB) ? p_lds[blk * RPB + lane] * ap_lds[lane] : 0.f;
            d = wave_reduce(d);
            if (lane == 0) AS(&g_part[buf][blk], d);
        }
        grid_barrier(blk, tid, base + (++bc));   // THE one barrier per iteration

        // ---- pAp reduce (redundant per block, fixed order) ----
        float u = (tid < NBLK) ? AL(&g_part[buf][tid]) : 0.f;
        float pAp = block_sum(u, red, lane, wv);
        float ak = rs / pAp;

        // ---- pass A: read full Ap; update x (owners), r (regs); local rs_new ----
        f32x4 ap4;
        #pragma unroll
        for (int i = 0; i < 4; ++i) ap4[i] = AL(&g_Ap[buf][e0 + i]);
        f32x4 p_old = *(const f32x4*)&p_lds[e0];
        if (owner) {
            #pragma unroll
            for (int i = 0; i < 4; ++i) x_reg[i] += ak * p_old[i];
        }
        #pragma unroll
        for (int i = 0; i < 4; ++i) r_reg[i] -= ak * ap4[i];
        float rs_new = block_sum(r_reg[0]*r_reg[0] + r_reg[1]*r_reg[1]
                               + r_reg[2]*r_reg[2] + r_reg[3]*r_reg[3],
                               red, lane, wv);
        float bk = rs_new / rs;
        rs = rs_new;

        // ---- pass B: p = r + bk*p (regs -> LDS) ----
        f32x4 p_new;
        #pragma unroll
        for (int i = 0; i < 4; ++i) p_new[i] = r_reg[i] + bk * p_old[i];
        *(f32x4*)&p_lds[e0] = p_new;
        __syncthreads();                  // p_lds ready for next matvec
    }

    // ---- write own x slice once ----
    if (owner) *(f32x4*)&x[e0] = x_reg;
}

extern "C" void kernel_launch(void* const* d_in, const int* in_sizes, int n_in,
                              void* d_out, int out_size, void* d_ws, size_t ws_size,
                              hipStream_t stream) {
    const float* A = (const float*)d_in[0];
    const float* b = (const float*)d_in[1];
    float* x = (float*)d_out;
    pcg_kernel<<<dim3(NBLK), dim3(NTHR), 0, stream>>>(A, b, x);
}

// Round 12
// 79.998 us; speedup vs baseline: 2.8392x; 1.7905x over previous
//
#include <hip/hip_runtime.h>

#define CGN    4096
#define NBLK   256
#define NTHR   1024
#define NW     (NTHR / 64)       // 16 waves/block
#define RPB    (CGN / NBLK)      // 16 rows per block (1 per wave)
#define MAX_IT 20
#define TOLF   1e-8f

typedef float f32x4 __attribute__((ext_vector_type(4)));

// Module-scope scratch (.bss). Deterministic: fully rewritten or monotonic.
// g_Ap parity double-buffered: with one barrier per iteration a block lags at
// most one publish behind, so the buffer being read is never being written.
__device__ float    g_Ap[2][CGN];
__device__ unsigned g_flags[NBLK];  // per-block arrival epochs (monotonic)
__device__ unsigned g_release;      // block-0-owned release epoch (monotonic)

// Relaxed agent-scope (sc-flagged, L3 coherence point) accesses: no cache
// maintenance instructions emitted; A stays warm in L2/L3 across iterations.
#define AL(p)   __hip_atomic_load((p), __ATOMIC_RELAXED, __HIP_MEMORY_SCOPE_AGENT)
#define AS(p,v) __hip_atomic_store((p), (v), __ATOMIC_RELAXED, __HIP_MEMORY_SCOPE_AGENT)

__device__ __forceinline__ float wave_reduce(float v) {
    #pragma unroll
    for (int off = 32; off > 0; off >>= 1)
        v += __shfl_down(v, off, 64);
    return v;  // lane 0 holds the sum
}

// Hierarchical flag barrier (proven r6/r7/r9): arrival = one sc-store/block;
// block 0 polls all flags then publishes one release word; others poll only
// the release word. __syncthreads() before arrival drains vmcnt (compiler
// emits s_waitcnt vmcnt(0) before s_barrier), so all data stores reached the
// coherence point first. Monotonic epochs => wrap-safe, replay-safe.
__device__ __forceinline__ void grid_barrier(int blk, int tid, unsigned target) {
    __syncthreads();
    if (tid == 0) AS(&g_flags[blk], target);
    if (blk == 0) {
        if (tid < NBLK) {
            while ((int)(AL(&g_flags[tid]) - target) < 0)
                __builtin_amdgcn_s_sleep(2);
        }
        __syncthreads();                 // all 256 flags confirmed
        if (tid == 0) AS(&g_release, target);
    } else {
        if (tid == 0) {
            while ((int)(AL(&g_release) - target) < 0)
                __builtin_amdgcn_s_sleep(2);
        }
    }
    __syncthreads();
}

// Three block-wide sums in ONE syncthreads round, broadcast to all threads.
// Fixed order => bit-identical results in every block (grid-uniform scalars).
__device__ __forceinline__ void block_sum3(float a, float b, float c,
                                           float* red, int lane, int wv,
                                           float* oa, float* ob, float* oc) {
    a = wave_reduce(a);
    b = wave_reduce(b);
    c = wave_reduce(c);
    __syncthreads();                     // protect previous use of red
    if (lane == 0) {
        red[wv]          = a;
        red[NW + wv]     = b;
        red[2 * NW + wv] = c;
    }
    __syncthreads();
    float ta = 0.f, tb = 0.f, tc = 0.f;
    #pragma unroll
    for (int i = 0; i < NW; ++i) {
        ta += red[i];
        tb += red[NW + i];
        tc += red[2 * NW + i];
    }
    *oa = ta; *ob = tb; *oc = tc;
}

__global__ __launch_bounds__(NTHR, 4) void pcg_kernel(
    const float* __restrict__ A, const float* __restrict__ b,
    float* __restrict__ x)
{
    __shared__ float p_lds[CGN];      // full p vector (mirror for matvec reads)
    __shared__ float red[3 * NW];

    const int tid  = threadIdx.x;
    const int blk  = blockIdx.x;
    const int lane = tid & 63;
    const int wv   = tid >> 6;
    const int e0   = tid * 4;                 // this thread's 4 elements
    const bool owner = (tid >> 2) == blk;     // 4 threads own the block's x-slice

    const unsigned base = AL(&g_flags[blk]);  // flags all equal between calls
    unsigned bc = 0;

    // ---- pin own A row-slice in 64 VGPRs via asm loads (not rematerializable) ----
    f32x4 arow[16];
    {
        const f32x4* bp = (const f32x4*)(A + (size_t)(blk * RPB + wv) * CGN) + lane;
        #pragma unroll
        for (int j = 0; j < 16; ++j) {
            const f32x4* addr = bp + j * 64;
            asm volatile("global_load_dwordx4 %0, %1, off"
                         : "=v"(arow[j]) : "v"(addr));
        }
    }

    // ---- init: r = b (regs), p = r (regs + LDS mirror), rs = b.b (local) ----
    f32x4 r_reg = ((const f32x4*)b)[tid];
    f32x4 p_reg = r_reg;
    f32x4 x_reg = {0.f, 0.f, 0.f, 0.f};
    *(f32x4*)&p_lds[e0] = p_reg;
    float rs, d1, d2;
    block_sum3(r_reg[0]*r_reg[0] + r_reg[1]*r_reg[1]
             + r_reg[2]*r_reg[2] + r_reg[3]*r_reg[3], 0.f, 0.f,
               red, lane, wv, &rs, &d1, &d2);
    // block_sum3's syncthreads also makes p_lds visible block-wide.

    asm volatile("s_waitcnt vmcnt(0)" ::: "memory");
    __builtin_amdgcn_sched_barrier(0);   // arow valid below this point

    for (int k = 0; k < MAX_IT; ++k) {
        if (!(rs >= TOLF * TOLF)) break;   // uniform across grid
        const int buf = k & 1;

        // ---- matvec from registers: wave wv computes row blk*RPB + wv ----
        float acc = 0.f;
        #pragma unroll
        for (int j = 0; j < 16; ++j) {
            f32x4 p4 = *(const f32x4*)&p_lds[(j * 64 + lane) * 4];
            acc += arow[j][0] * p4[0] + arow[j][1] * p4[1]
                 + arow[j][2] * p4[2] + arow[j][3] * p4[3];
        }
        acc = wave_reduce(acc);
        if (lane == 0) AS(&g_Ap[buf][blk * RPB + wv], acc);  // publish own Ap row

        grid_barrier(blk, tid, base + (++bc));   // THE one barrier per iteration

        // ---- read full Ap slice (4 elements), all sums block-local ----
        f32x4 ap4;
        #pragma unroll
        for (int i = 0; i < 4; ++i) ap4[i] = AL(&g_Ap[buf][e0 + i]);

        // ---- fused 3-dot reduction: pAp, rAp, ApAp in one sync round ----
        float pAp, rAp, ApAp;
        block_sum3(p_reg[0]*ap4[0] + p_reg[1]*ap4[1]
                 + p_reg[2]*ap4[2] + p_reg[3]*ap4[3],
                   r_reg[0]*ap4[0] + r_reg[1]*ap4[1]
                 + r_reg[2]*ap4[2] + r_reg[3]*ap4[3],
                   ap4[0]*ap4[0] + ap4[1]*ap4[1]
                 + ap4[2]*ap4[2] + ap4[3]*ap4[3],
                   red, lane, wv, &pAp, &rAp, &ApAp);

        float ak = rs / pAp;
        // merged-dot CG identity: ||r - ak*Ap||^2 = rs - 2ak*(r.Ap) + ak^2*(Ap.Ap)
        float rs_new = rs - 2.f * ak * rAp + ak * ak * ApAp;
        float bk = rs_new / rs;
        rs = rs_new;

        // ---- local updates: x (owners), r, p; mirror p to LDS ----
        if (owner) {
            #pragma unroll
            for (int i = 0; i < 4; ++i) x_reg[i] += ak * p_reg[i];
        }
        #pragma unroll
        for (int i = 0; i < 4; ++i) {
            r_reg[i] -= ak * ap4[i];
            p_reg[i]  = r_reg[i] + bk * p_reg[i];
        }
        *(f32x4*)&p_lds[e0] = p_reg;
        __syncthreads();                  // p_lds ready for next matvec
    }

    // ---- write own x slice once ----
    if (owner) *(f32x4*)&x[e0] = x_reg;
}

extern "C" void kernel_launch(void* const* d_in, const int* in_sizes, int n_in,
                              void* d_out, int out_size, void* d_ws, size_t ws_size,
                              hipStream_t stream) {
    const float* A = (const float*)d_in[0];
    const float* b = (const float*)d_in[1];
    float* x = (float*)d_out;
    pcg_kernel<<<dim3(NBLK), dim3(NTHR), 0, stream>>>(A, b, x);
}